// Round 14
// baseline (117.536 us; speedup 1.0000x reference)
//
#include <hip/hip_runtime.h>
#include <hip/hip_bf16.h>
#include <stdint.h>

#define SEQ    2048
#define DM     512
#define NHEAD  8
#define HD     64
#define BATCH  4
#define MTOT   (BATCH*SEQ)   // 8192

typedef __attribute__((ext_vector_type(4)))  float  f32x4;
typedef __attribute__((ext_vector_type(16))) float  f32x16;
typedef __attribute__((ext_vector_type(8))) short  bf16x8;
typedef __attribute__((ext_vector_type(8))) unsigned short u16x8;
typedef __attribute__((ext_vector_type(4))) unsigned short u16x4;
typedef __attribute__((ext_vector_type(4))) float  fl4;
typedef __attribute__((ext_vector_type(2))) unsigned u32x2;
typedef __attribute__((ext_vector_type(4))) unsigned u32x4;

__device__ __forceinline__ unsigned short f2bf(float f) {
  union { float f; unsigned u; } c; c.f = f;
  return (unsigned short)((c.u + 0x7fffu + ((c.u >> 16) & 1u)) >> 16);
}

__device__ __forceinline__ float bf2f(unsigned short s) {
  unsigned u = (unsigned)s << 16;
  float f; __builtin_memcpy(&f, &u, 4);
  return f;
}

__device__ __forceinline__ void load_lds16(const void* g, void* l) {
  __builtin_amdgcn_global_load_lds((__attribute__((address_space(1))) void*)g,
                                   (__attribute__((address_space(3))) void*)l,
                                   16, 0, 0);
}

// hardware transpose read: 64b per lane, 16-bit element transpose in 16-lane groups
__device__ __forceinline__ u32x2 ds_tr16(const void* p) {
  u32x2 r;
  asm volatile("ds_read_b64_tr_b16 %0, %1"
               : "=v"(r)
               : "v"((__attribute__((address_space(3))) const void*)p));
  return r;
}

// packed f32 pair -> bf16x2 dword (v_cvt_pk_bf16_f32)
__device__ __forceinline__ unsigned pack_bf2(float lo, float hi) {
  __hip_bfloat162 h2 = __float22bfloat162_rn(float2{lo, hi});
  unsigned u; __builtin_memcpy(&u, &h2, 4);
  return u;
}

// ---------------- merged preprocessing: casts + weight transposes -----------
__global__ void k_pre(const float* __restrict__ X, unsigned short* __restrict__ Xb,
                      const float* __restrict__ C, unsigned short* __restrict__ Cb,
                      const float* __restrict__ Wq, unsigned short* __restrict__ Wqt,
                      const float* __restrict__ Wkv, unsigned short* __restrict__ Wkvt,
                      const float* __restrict__ Wo, unsigned short* __restrict__ Wot) {
  __shared__ __align__(16) unsigned short t[64][66];
  int bid = blockIdx.x, tid = threadIdx.x;
  if (bid < 8192) {
    const float* src = (bid < 4096) ? X : C;
    unsigned short* dst = (bid < 4096) ? Xb : Cb;
    int i = (bid & 4095) * 256 + tid;
    fl4 v = *(const fl4*)(src + (size_t)i * 4);
    u32x2 o;
    o[0] = pack_bf2(v[0], v[1]);
    o[1] = pack_bf2(v[2], v[3]);
    *(u32x2*)((void*)(dst + (size_t)i * 4)) = o;
    return;
  }
  int tjob = bid - 8192;
  const float* W; unsigned short* Wt; int Nd, bx, by;
  if (tjob < 64)       { W = Wq;  Wt = Wqt;  Nd = 512;  bx = tjob & 7;  by = tjob >> 3; }
  else if (tjob < 192) { int u = tjob - 64;  W = Wkv; Wt = Wkvt; Nd = 1024; bx = u & 15; by = u >> 4; }
  else                 { int u = tjob - 192; W = Wo;  Wt = Wot;  Nd = 512;  bx = u & 7;  by = u >> 3; }
  int k0 = by * 64, n0 = bx * 64;
  int r = tid >> 2, cs = (tid & 3) * 16;
  const float* src = W + (size_t)(k0 + r) * Nd + n0 + cs;
#pragma unroll
  for (int i = 0; i < 4; ++i) {
    fl4 v = *(const fl4*)(src + i * 4);
    *(unsigned*)&t[r][cs + i*4]     = pack_bf2(v[0], v[1]);
    *(unsigned*)&t[r][cs + i*4 + 2] = pack_bf2(v[2], v[3]);
  }
  __syncthreads();
  unsigned short* drow = Wt + (size_t)(n0 + r) * 512 + k0 + cs;
#pragma unroll
  for (int half = 0; half < 2; ++half) {
    u16x8 o;
#pragma unroll
    for (int i = 0; i < 8; ++i) o[i] = t[cs + half*8 + i][r];
    *(u16x8*)(drow + half * 8) = o;
  }
}

// ------ 128x64-tile GEMM, 2-phase prefetch double-buffered ------------------
template<int RESID>
__device__ __forceinline__ void gemm128x64(
    const unsigned short* __restrict__ A,
    const unsigned short* __restrict__ Bt,
    const float* __restrict__ bias,
    const unsigned short* __restrict__ res,
    unsigned short* __restrict__ Cout,
    int N, int K, int m0, int n0, float osc,
    unsigned short* Als, unsigned short* Bls) {
  int tid  = threadIdx.x;
  int lane = tid & 63, wave = tid >> 6;
  int q = lane & 15, lk = lane >> 4;
  f32x4 acc[2][4];
#pragma unroll
  for (int mt = 0; mt < 2; ++mt)
#pragma unroll
    for (int nt = 0; nt < 4; ++nt) acc[mt][nt] = f32x4{0.f,0.f,0.f,0.f};

  const unsigned short* gA[4];
#pragma unroll
  for (int it = 0; it < 4; ++it) {
    int idx = tid + it * 256;
    int row = idx >> 3, ch = idx & 7, sc = ch ^ (row & 7);
    gA[it] = A + (size_t)(m0 + row) * K + sc * 8;
  }
  const unsigned short* gB[2];
#pragma unroll
  for (int it = 0; it < 2; ++it) {
    int idx = tid + it * 256;
    int row = idx >> 3, ch = idx & 7, sc = ch ^ (row & 7);
    gB[it] = Bt + (size_t)(n0 + row) * K + sc * 8;
  }
  char* aD = (char*)Als + tid * 16;
  char* bD = (char*)Bls + tid * 16;

#pragma unroll
  for (int it = 0; it < 4; ++it) { load_lds16(gA[it], aD + it * 4096); gA[it] += 64; }
#pragma unroll
  for (int it = 0; it < 2; ++it) { load_lds16(gB[it], bD + it * 4096); gB[it] += 64; }
  __syncthreads();

  int nkb = K >> 6;
  int buf = 0;
  for (int kb = 0; kb < nkb; ++kb) {
    if (kb + 1 < nkb) {
      char* aN = aD + (buf ^ 1) * 16384;
      char* bN = bD + (buf ^ 1) * 8192;
#pragma unroll
      for (int it = 0; it < 4; ++it) { load_lds16(gA[it], aN + it * 4096); gA[it] += 64; }
#pragma unroll
      for (int it = 0; it < 2; ++it) { load_lds16(gB[it], bN + it * 4096); gB[it] += 64; }
    }
    const char* aR = (const char*)Als + buf * 16384;
    const char* bR = (const char*)Bls + buf * 8192;
#pragma unroll
    for (int ks = 0; ks < 2; ++ks) {
      bf16x8 a[2], b[4];
#pragma unroll
      for (int mt = 0; mt < 2; ++mt) {
        int row = wave * 32 + mt * 16 + q;
        a[mt] = *(const bf16x8*)(aR + row * 128 + (((ks*4 + lk) ^ (row & 7)) * 16));
      }
#pragma unroll
      for (int nt = 0; nt < 4; ++nt) {
        int row = nt * 16 + q;
        b[nt] = *(const bf16x8*)(bR + row * 128 + (((ks*4 + lk) ^ (row & 7)) * 16));
      }
#pragma unroll
      for (int mt = 0; mt < 2; ++mt)
#pragma unroll
        for (int nt = 0; nt < 4; ++nt)
          acc[mt][nt] = __builtin_amdgcn_mfma_f32_16x16x32_bf16(a[mt], b[nt], acc[mt][nt], 0, 0, 0);
    }
    __syncthreads();
    buf ^= 1;
  }
#pragma unroll
  for (int nt = 0; nt < 4; ++nt) {
    int col = n0 + nt * 16 + q;
    float bv = bias[col];
#pragma unroll
    for (int mt = 0; mt < 2; ++mt) {
      int rowb = m0 + wave * 32 + mt * 16 + lk * 4;
#pragma unroll
      for (int rr = 0; rr < 4; ++rr) {
        float v = acc[mt][nt][rr] + bv;
        size_t off = (size_t)(rowb + rr) * N + col;
        if (RESID) Cout[off] = f2bf(v + bf2f(res[off]));
        else       Cout[off] = f2bf(v * osc);
      }
    }
  }
}

// merged Q-proj + KV-proj. grid 1536 (XCD-swizzled): l<512 -> Q, else KV.
__global__ __launch_bounds__(256, 3)
void k_projmm(const unsigned short* __restrict__ Xb, const unsigned short* __restrict__ Cb,
              const unsigned short* __restrict__ Wqt, const unsigned short* __restrict__ Wkvt,
              const float* __restrict__ bq, const float* __restrict__ bkv,
              unsigned short* __restrict__ Qb, unsigned short* __restrict__ KVb) {
  __shared__ __align__(16) unsigned short Als[2 * 128 * 64];
  __shared__ __align__(16) unsigned short Bls[2 * 64 * 64];
  int bid = blockIdx.x;
  int l = (bid & 7) * 192 + (bid >> 3);
  const float c1 = 0.125f * 1.44269504088896340736f;
  if (l < 512) {
    int m = l >> 3, n = l & 7;
    gemm128x64<0>(Xb, Wqt, bq, nullptr, Qb, 512, 512, m * 128, n * 64, c1, Als, Bls);
  } else {
    int l2 = l - 512;
    int m = l2 >> 4, n = l2 & 15;
    gemm128x64<0>(Cb, Wkvt, bkv, nullptr, KVb, 1024, 512, m * 128, n * 64, 1.0f, Als, Bls);
  }
}

// O-proj + bias + bf16 residual -> bf16 tmp. grid 512 (XCD-swizzled).
__global__ __launch_bounds__(256, 3)
void k_omm(const unsigned short* __restrict__ Abuf, const unsigned short* __restrict__ Wot,
           const float* __restrict__ bo, const unsigned short* __restrict__ residb,
           unsigned short* __restrict__ tmp) {
  __shared__ __align__(16) unsigned short Als[2 * 128 * 64];
  __shared__ __align__(16) unsigned short Bls[2 * 64 * 64];
  int bid = blockIdx.x;
  int l = (bid & 7) * 64 + (bid >> 3);
  int m = l >> 3, n = l & 7;
  gemm128x64<1>(Abuf, Wot, bo, residb, tmp, 512, 512, m * 128, n * 64, 1.0f, Als, Bls);
}

// ---------------- flash attention v12: 32x32x16 MFMA -------------------------
// grid 1024 (XCD-swizzled): 32 (b,h) * 32 q-tiles(64); 2 waves * 32 q-rows;
// 128 threads/block, KVBLK=32, 20 KB LDS -> 8 blocks/CU (16 waves/CU).
// Swapped QK: S^T[32tok][32q] = sum_s mfma32(K[s], Q[s]) over 4 d-steps.
// C/D: col=lane&31, row=(reg&3)+8(reg>>2)+4(lane>>5). P-network: 2
// permlane32_swap per 16-token step. V staged via global_load_lds into the
// region map [dt][s][u][g:4tok x 16dv tiles], consumed by 8 ds_read_b64_tr_b16.
// No-max softmax (Q pre-scaled by 0.125*log2e); deferred row-sum.
__global__ __launch_bounds__(128, 4)
void k_attn(const unsigned short* __restrict__ Qb,
            const unsigned short* __restrict__ KVb,
            unsigned short* __restrict__ Ab) {
  __shared__ __align__(16) unsigned short Klds[2][2048];
  __shared__ __align__(16) unsigned short Vlds[3][2048];
  int tid  = threadIdx.x;
  int lane = tid & 63, wv = tid >> 6;
  int q    = lane & 31, hf = lane >> 5;
  int bid = blockIdx.x;
  int swz = (bid & 7) * 128 + (bid >> 3);   // 128 blocks (4 bh) per XCD
  int qt = swz & 31, bh = swz >> 5;
  int b  = bh >> 3, hd = bh & 7;
  int q0 = qt * 64 + wv * 32;
  const size_t kvbase = (size_t)b * SEQ * 1024;

  // Q fragments: 4 d-steps of K=16 (B-operand: col=lane&31=q, k=hf*8+i)
  bf16x8 qf[4];
  {
    size_t qrow = (size_t)b * SEQ + q0 + q;
    const unsigned short* qp = Qb + qrow * DM + hd * HD + hf * 8;
#pragma unroll
    for (int s = 0; s < 4; ++s) qf[s] = *(const bf16x8*)(qp + s * 16);
  }
  f32x16 acc[2];
#pragma unroll
  for (int i = 0; i < 16; ++i) { acc[0][i] = 0.f; acc[1][i] = 0.f; }
  float l = 0.f;
  u32x4 pbB[2];

  // ---- staging pointers (advance += 32768 u16 per 32-token tile) ----
  const unsigned short *gK0, *gK1, *gV0, *gV1;
  {
    int i0 = tid, i1 = tid + 128;
    int r0 = i0 >> 3, c0 = (i0 & 7) ^ (r0 & 7);
    gK0 = KVb + kvbase + (size_t)r0 * 1024 + hd * HD + c0 * 8;
    int r1 = i1 >> 3, c1 = (i1 & 7) ^ (r1 & 7);
    gK1 = KVb + kvbase + (size_t)r1 * 1024 + hd * HD + c1 * 8;
    // V region map: off = dt*2048 + s*1024 + u*512 + g*128 + j*32 + half*16
    // tile g holds tokens s*16+(g>>1)*8+u*4+j, dv chunk dt*32+(g&1)*16+half*8
    int o0 = i0 * 16;
    int dt0 = o0 >> 11, r_ = o0 & 2047;
    int s0 = r_ >> 10; r_ &= 1023;
    int u0 = r_ >> 9;  r_ &= 511;
    int g0 = r_ >> 7;  r_ &= 127;
    int j0 = r_ >> 5;
    int hh0 = (r_ >> 4) & 1;
    int t0 = s0 * 16 + (g0 >> 1) * 8 + u0 * 4 + j0;
    int dv0 = dt0 * 32 + (g0 & 1) * 16 + hh0 * 8;
    gV0 = KVb + kvbase + (size_t)t0 * 1024 + 512 + hd * HD + dv0;
    int o1 = i1 * 16;
    int dt1 = o1 >> 11; r_ = o1 & 2047;
    int s1 = r_ >> 10; r_ &= 1023;
    int u1 = r_ >> 9;  r_ &= 511;
    int g1 = r_ >> 7;  r_ &= 127;
    int j1 = r_ >> 5;
    int hh1 = (r_ >> 4) & 1;
    int t1 = s1 * 16 + (g1 >> 1) * 8 + u1 * 4 + j1;
    int dv1 = dt1 * 32 + (g1 & 1) * 16 + hh1 * 8;
    gV1 = KVb + kvbase + (size_t)t1 * 1024 + 512 + hd * HD + dv1;
  }
  char* kdA = (char*)Klds[0] + tid * 16;
  char* kdB = (char*)Klds[1] + tid * 16;
  char* vdA = (char*)Vlds[0] + tid * 16;
  char* vdB = (char*)Vlds[1] + tid * 16;
  char* vdC = (char*)Vlds[2] + tid * 16;
  const char* krA = (const char*)Klds[0];
  const char* krB = (const char*)Klds[1];
  const char* vsA = (const char*)Vlds[0] + lane * 8;
  const char* vsB = (const char*)Vlds[1] + lane * 8;
  const char* vsC = (const char*)Vlds[2] + lane * 8;

#define STAGE(kd_, vd_) do {                        \
    load_lds16(gK0, (kd_));                         \
    load_lds16(gK1, (kd_) + 2048);                  \
    load_lds16(gV0, (vd_));                         \
    load_lds16(gV1, (vd_) + 2048);                  \
    gK0 += 32768; gK1 += 32768;                     \
    gV0 += 32768; gV1 += 32768;                     \
  } while (0)

  // prologue: tile 0 -> K buf0, V buf0
  STAGE(kdA, vdA);
  __syncthreads();

  const int NT = SEQ / 32;   // 64 tiles
  int kc = 0;        // K buffer holding tile kb
  int vn = 1;        // V stage target  = (kb+1)%3
  int vp = 2;        // V PV source     = (kb-1)%3 (valid for kb>=1)
  for (int kb = 0; kb < NT; ++kb) {
    // stage tile kb+1
    if (kb < NT - 1) {
      char* kd = kc ? kdA : kdB;
      char* vd = (vn == 0) ? vdA : ((vn == 1) ? vdB : vdC);
      STAGE(kd, vd);
    }

    // ---- PV(kb-1): 8 tr-reads + 4 MFMA (lagged one tile) ----
    if (kb > 0) {
      const char* vsrc = (vp == 0) ? vsA : ((vp == 1) ? vsB : vsC);
      u32x2 tr[2][2][2];   // [dt][s][u]
#pragma unroll
      for (int dt = 0; dt < 2; ++dt)
#pragma unroll
        for (int s = 0; s < 2; ++s)
#pragma unroll
          for (int u = 0; u < 2; ++u)
            tr[dt][s][u] = ds_tr16(vsrc + dt * 2048 + s * 1024 + u * 512);
      asm volatile("s_waitcnt lgkmcnt(0)" ::: "memory");
      __builtin_amdgcn_sched_barrier(0);
      __builtin_amdgcn_s_setprio(1);
#pragma unroll
      for (int s = 0; s < 2; ++s) {
        union { u32x4 u; bf16x8 v; } pb;
        pb.u = pbB[s];
#pragma unroll
        for (int dt = 0; dt < 2; ++dt) {
          union { u32x4 u; bf16x8 v; } cv;
          cv.u[0] = tr[dt][s][0][0]; cv.u[1] = tr[dt][s][0][1];
          cv.u[2] = tr[dt][s][1][0]; cv.u[3] = tr[dt][s][1][1];
          acc[dt] = __builtin_amdgcn_mfma_f32_32x32x16_bf16(cv.v, pb.v, acc[dt], 0, 0, 0);
        }
      }
      __builtin_amdgcn_s_setprio(0);
    }

    // ---- QK^T (swapped): st = S^T[tok=lane&31+...][q] over 4 d-steps ----
    const char* kr = kc ? krB : krA;
    f32x16 st;
#pragma unroll
    for (int i = 0; i < 16; ++i) st[i] = 0.f;
    __builtin_amdgcn_s_setprio(1);
#pragma unroll
    for (int s = 0; s < 4; ++s) {
      bf16x8 kf = *(const bf16x8*)(kr + q * 128 + (((s * 2 + hf) ^ (q & 7)) * 16));
      st = __builtin_amdgcn_mfma_f32_32x32x16_bf16(kf, qf[s], st, 0, 0, 0);
    }
    __builtin_amdgcn_s_setprio(0);

    // ---- softmax: p = exp2(s) off MFMA; deferred row-sum; 2-swap network ----
    float p[16];
#pragma unroll
    for (int i = 0; i < 16; ++i) {
      p[i] = __builtin_amdgcn_exp2f(st[i]);
      l += p[i];
    }
    unsigned pk[8];
#pragma unroll
    for (int m = 0; m < 8; ++m) pk[m] = pack_bf2(p[2*m], p[2*m + 1]);
    // token t(reg) = (reg&3)+8*(reg>>2)+4*hf; pk[m] covers t=8*(m>>1)+4hf+2(m&1)
    // B-frag dword e at half h <- pk[4s+2h+(e&1)] from half e>>1:
#pragma unroll
    for (int s = 0; s < 2; ++s) {
      unsigned u0 = pk[4*s + 0], w0 = pk[4*s + 2];
      unsigned u1 = pk[4*s + 1], w1 = pk[4*s + 3];
      asm("v_permlane32_swap_b32 %0, %1" : "+v"(u0), "+v"(w0));
      asm("v_permlane32_swap_b32 %0, %1" : "+v"(u1), "+v"(w1));
      pbB[s][0] = u0; pbB[s][1] = u1;
      pbB[s][2] = w0; pbB[s][3] = w1;
    }

    __syncthreads();
    kc ^= 1;
    vn = (vn == 2) ? 0 : vn + 1;
    vp = (vp == 2) ? 0 : vp + 1;
  }

  // ---- final lagged PV(NT-1) ----
  {
    const char* vsrc = (vp == 0) ? vsA : ((vp == 1) ? vsB : vsC);
    u32x2 tr[2][2][2];
#pragma unroll
    for (int dt = 0; dt < 2; ++dt)
#pragma unroll
      for (int s = 0; s < 2; ++s)
#pragma unroll
        for (int u = 0; u < 2; ++u)
          tr[dt][s][u] = ds_tr16(vsrc + dt * 2048 + s * 1024 + u * 512);
    asm volatile("s_waitcnt lgkmcnt(0)" ::: "memory");
    __builtin_amdgcn_sched_barrier(0);
#pragma unroll
    for (int s = 0; s < 2; ++s) {
      union { u32x4 u; bf16x8 v; } pb;
      pb.u = pbB[s];
#pragma unroll
      for (int dt = 0; dt < 2; ++dt) {
        union { u32x4 u; bf16x8 v; } cv;
        cv.u[0] = tr[dt][s][0][0]; cv.u[1] = tr[dt][s][0][1];
        cv.u[2] = tr[dt][s][1][0]; cv.u[3] = tr[dt][s][1][1];
        acc[dt] = __builtin_amdgcn_mfma_f32_32x32x16_bf16(cv.v, pb.v, acc[dt], 0, 0, 0);
      }
    }
  }

  // ---- deferred row-sum (halves at hf=0/1) + epilogue ----
  l += __shfl_xor(l, 32);
  float inv = 1.0f / l;
  size_t orow = ((size_t)b * SEQ + q0 + q) * DM + hd * HD;
#pragma unroll
  for (int dt = 0; dt < 2; ++dt)
#pragma unroll
    for (int rg = 0; rg < 4; ++rg) {
      u16x4 o;
#pragma unroll
      for (int rr = 0; rr < 4; ++rr) o[rr] = f2bf(acc[dt][rg * 4 + rr] * inv);
      *(u16x4*)(Ab + orow + dt * 32 + rg * 8 + hf * 4) = o;
    }
#undef STAGE
}

// ---------------- LayerNorm (wave per row, bf16 input) ----------------
__global__ void k_ln(const unsigned short* __restrict__ x, const float* __restrict__ gamma,
                     const float* __restrict__ beta, float* __restrict__ out) {
  int tid = threadIdx.x, lane = tid & 63, wave = tid >> 6;
  size_t row = (size_t)blockIdx.x * 4 + wave;
  u16x8 xv = *(const u16x8*)(x + row * DM + lane * 8);
  float v[8];
#pragma unroll
  for (int i = 0; i < 8; ++i) v[i] = bf2f(xv[i]);
  float s  = (v[0]+v[1]) + (v[2]+v[3]) + (v[4]+v[5]) + (v[6]+v[7]);
  float ss = (v[0]*v[0]+v[1]*v[1]) + (v[2]*v[2]+v[3]*v[3])
           + (v[4]*v[4]+v[5]*v[5]) + (v[6]*v[6]+v[7]*v[7]);
#pragma unroll
  for (int off = 1; off < 64; off <<= 1) {
    s  += __shfl_xor(s, off);
    ss += __shfl_xor(ss, off);
  }
  float mu  = s * (1.0f / DM);
  float var = ss * (1.0f / DM) - mu * mu;
  float w = rsqrtf(var + 1e-5f);
  fl4 g0 = *(const fl4*)(gamma + lane*8), g1 = *(const fl4*)(gamma + lane*8 + 4);
  fl4 b0 = *(const fl4*)(beta + lane*8),  b1 = *(const fl4*)(beta + lane*8 + 4);
  fl4 o0, o1;
#pragma unroll
  for (int i = 0; i < 4; ++i) {
    o0[i] = (v[i]     - mu) * w * g0[i] + b0[i];
    o1[i] = (v[4 + i] - mu) * w * g1[i] + b1[i];
  }
  float* orow = out + row * DM + lane * 8;
  *(fl4*)orow = o0;
  *(fl4*)(orow + 4) = o1;
}

extern "C" void kernel_launch(void* const* d_in, const int* in_sizes, int n_in,
                              void* d_out, int out_size, void* d_ws, size_t ws_size,
                              hipStream_t stream) {
  const float* layer_input = (const float*)d_in[0];
  const float* cross       = (const float*)d_in[1];
  const float* Wq   = (const float*)d_in[2];
  const float* bq   = (const float*)d_in[3];
  const float* Wkv  = (const float*)d_in[4];
  const float* bkv  = (const float*)d_in[5];
  const float* Wo   = (const float*)d_in[6];
  const float* bo   = (const float*)d_in[7];
  const float* gamma = (const float*)d_in[8];
  const float* beta  = (const float*)d_in[9];
  float* out = (float*)d_out;

  char* ws = (char*)d_ws;
  unsigned short* Xb   = (unsigned short*)(ws + (size_t)0);
  unsigned short* Cb   = (unsigned short*)(ws + ((size_t)8  << 20));
  unsigned short* Qb   = (unsigned short*)(ws + ((size_t)16 << 20));
  unsigned short* KVb  = (unsigned short*)(ws + ((size_t)24 << 20));
  unsigned short* Abuf = (unsigned short*)(ws + ((size_t)40 << 20));
  unsigned short* tmpb = (unsigned short*)(ws + ((size_t)48 << 20));
  unsigned short* Wqt  = (unsigned short*)(ws + ((size_t)64 << 20));
  unsigned short* Wkvt = (unsigned short*)(ws + ((size_t)65 << 20));
  unsigned short* Wot  = (unsigned short*)(ws + ((size_t)67 << 20));

  // preprocessing: both casts + all 3 weight transposes
  k_pre<<<8448, 256, 0, stream>>>(layer_input, Xb, cross, Cb,
                                  Wq, Wqt, Wkv, Wkvt, Wo, Wot);
  // merged Q + KV projections (Q pre-scaled by 0.125*log2e)
  k_projmm<<<1536, 256, 0, stream>>>(Xb, Cb, Wqt, Wkvt, bq, bkv, Qb, KVb);
  // attention (1024 blocks x 128 threads, XCD-swizzled; 8 blocks/CU)
  k_attn<<<1024, 128, 0, stream>>>(Qb, KVb, Abuf);
  // output projection + bias + bf16 residual -> bf16 tmp
  k_omm<<<512, 256, 0, stream>>>(Abuf, Wot, bo, Xb, tmpb);
  // layernorm (bf16 in, f32 out)
  k_ln<<<MTOT/4, 256, 0, stream>>>(tmpb, gamma, beta, out);
}

// Round 15
// 107.225 us; speedup vs baseline: 1.0962x; 1.0962x over previous
//
#include <hip/hip_runtime.h>
#include <hip/hip_bf16.h>
#include <stdint.h>

#define SEQ    2048
#define DM     512
#define NHEAD  8
#define HD     64
#define BATCH  4
#define MTOT   (BATCH*SEQ)   // 8192

typedef __attribute__((ext_vector_type(4))) float  f32x4;
typedef __attribute__((ext_vector_type(8))) short  bf16x8;
typedef __attribute__((ext_vector_type(8))) unsigned short u16x8;
typedef __attribute__((ext_vector_type(4))) unsigned short u16x4;
typedef __attribute__((ext_vector_type(4))) float  fl4;
typedef __attribute__((ext_vector_type(2))) unsigned u32x2;
typedef __attribute__((ext_vector_type(4))) unsigned u32x4;

__device__ __forceinline__ unsigned short f2bf(float f) {
  union { float f; unsigned u; } c; c.f = f;
  return (unsigned short)((c.u + 0x7fffu + ((c.u >> 16) & 1u)) >> 16);
}

__device__ __forceinline__ float bf2f(unsigned short s) {
  unsigned u = (unsigned)s << 16;
  float f; __builtin_memcpy(&f, &u, 4);
  return f;
}

__device__ __forceinline__ void load_lds16(const void* g, void* l) {
  __builtin_amdgcn_global_load_lds((__attribute__((address_space(1))) void*)g,
                                   (__attribute__((address_space(3))) void*)l,
                                   16, 0, 0);
}

// hardware transpose read: 64b per lane, 16-bit element transpose in 16-lane groups
__device__ __forceinline__ u32x2 ds_tr16(const void* p) {
  u32x2 r;
  asm volatile("ds_read_b64_tr_b16 %0, %1"
               : "=v"(r)
               : "v"((__attribute__((address_space(3))) const void*)p));
  return r;
}

// packed f32 pair -> bf16x2 dword (v_cvt_pk_bf16_f32)
__device__ __forceinline__ unsigned pack_bf2(float lo, float hi) {
  __hip_bfloat162 h2 = __float22bfloat162_rn(float2{lo, hi});
  unsigned u; __builtin_memcpy(&u, &h2, 4);
  return u;
}

// ---------------- merged preprocessing: casts + weight transposes -----------
__global__ void k_pre(const float* __restrict__ X, unsigned short* __restrict__ Xb,
                      const float* __restrict__ C, unsigned short* __restrict__ Cb,
                      const float* __restrict__ Wq, unsigned short* __restrict__ Wqt,
                      const float* __restrict__ Wkv, unsigned short* __restrict__ Wkvt,
                      const float* __restrict__ Wo, unsigned short* __restrict__ Wot) {
  __shared__ __align__(16) unsigned short t[64][66];
  int bid = blockIdx.x, tid = threadIdx.x;
  if (bid < 8192) {
    const float* src = (bid < 4096) ? X : C;
    unsigned short* dst = (bid < 4096) ? Xb : Cb;
    int i = (bid & 4095) * 256 + tid;
    fl4 v = *(const fl4*)(src + (size_t)i * 4);
    u32x2 o;
    o[0] = pack_bf2(v[0], v[1]);
    o[1] = pack_bf2(v[2], v[3]);
    *(u32x2*)((void*)(dst + (size_t)i * 4)) = o;
    return;
  }
  int tjob = bid - 8192;
  const float* W; unsigned short* Wt; int Nd, bx, by;
  if (tjob < 64)       { W = Wq;  Wt = Wqt;  Nd = 512;  bx = tjob & 7;  by = tjob >> 3; }
  else if (tjob < 192) { int u = tjob - 64;  W = Wkv; Wt = Wkvt; Nd = 1024; bx = u & 15; by = u >> 4; }
  else                 { int u = tjob - 192; W = Wo;  Wt = Wot;  Nd = 512;  bx = u & 7;  by = u >> 3; }
  int k0 = by * 64, n0 = bx * 64;
  int r = tid >> 2, cs = (tid & 3) * 16;
  const float* src = W + (size_t)(k0 + r) * Nd + n0 + cs;
#pragma unroll
  for (int i = 0; i < 4; ++i) {
    fl4 v = *(const fl4*)(src + i * 4);
    *(unsigned*)&t[r][cs + i*4]     = pack_bf2(v[0], v[1]);
    *(unsigned*)&t[r][cs + i*4 + 2] = pack_bf2(v[2], v[3]);
  }
  __syncthreads();
  unsigned short* drow = Wt + (size_t)(n0 + r) * 512 + k0 + cs;
#pragma unroll
  for (int half = 0; half < 2; ++half) {
    u16x8 o;
#pragma unroll
    for (int i = 0; i < 8; ++i) o[i] = t[cs + half*8 + i][r];
    *(u16x8*)(drow + half * 8) = o;
  }
}

// ------ 128x64-tile GEMM, 2-phase prefetch double-buffered ------------------
template<int RESID>
__device__ __forceinline__ void gemm128x64(
    const unsigned short* __restrict__ A,
    const unsigned short* __restrict__ Bt,
    const float* __restrict__ bias,
    const unsigned short* __restrict__ res,
    unsigned short* __restrict__ Cout,
    int N, int K, int m0, int n0, float osc,
    unsigned short* Als, unsigned short* Bls) {
  int tid  = threadIdx.x;
  int lane = tid & 63, wave = tid >> 6;
  int q = lane & 15, lk = lane >> 4;
  f32x4 acc[2][4];
#pragma unroll
  for (int mt = 0; mt < 2; ++mt)
#pragma unroll
    for (int nt = 0; nt < 4; ++nt) acc[mt][nt] = f32x4{0.f,0.f,0.f,0.f};

  const unsigned short* gA[4];
#pragma unroll
  for (int it = 0; it < 4; ++it) {
    int idx = tid + it * 256;
    int row = idx >> 3, ch = idx & 7, sc = ch ^ (row & 7);
    gA[it] = A + (size_t)(m0 + row) * K + sc * 8;
  }
  const unsigned short* gB[2];
#pragma unroll
  for (int it = 0; it < 2; ++it) {
    int idx = tid + it * 256;
    int row = idx >> 3, ch = idx & 7, sc = ch ^ (row & 7);
    gB[it] = Bt + (size_t)(n0 + row) * K + sc * 8;
  }
  char* aD = (char*)Als + tid * 16;
  char* bD = (char*)Bls + tid * 16;

#pragma unroll
  for (int it = 0; it < 4; ++it) { load_lds16(gA[it], aD + it * 4096); gA[it] += 64; }
#pragma unroll
  for (int it = 0; it < 2; ++it) { load_lds16(gB[it], bD + it * 4096); gB[it] += 64; }
  __syncthreads();

  int nkb = K >> 6;
  int buf = 0;
  for (int kb = 0; kb < nkb; ++kb) {
    if (kb + 1 < nkb) {
      char* aN = aD + (buf ^ 1) * 16384;
      char* bN = bD + (buf ^ 1) * 8192;
#pragma unroll
      for (int it = 0; it < 4; ++it) { load_lds16(gA[it], aN + it * 4096); gA[it] += 64; }
#pragma unroll
      for (int it = 0; it < 2; ++it) { load_lds16(gB[it], bN + it * 4096); gB[it] += 64; }
    }
    const char* aR = (const char*)Als + buf * 16384;
    const char* bR = (const char*)Bls + buf * 8192;
#pragma unroll
    for (int ks = 0; ks < 2; ++ks) {
      bf16x8 a[2], b[4];
#pragma unroll
      for (int mt = 0; mt < 2; ++mt) {
        int row = wave * 32 + mt * 16 + q;
        a[mt] = *(const bf16x8*)(aR + row * 128 + (((ks*4 + lk) ^ (row & 7)) * 16));
      }
#pragma unroll
      for (int nt = 0; nt < 4; ++nt) {
        int row = nt * 16 + q;
        b[nt] = *(const bf16x8*)(bR + row * 128 + (((ks*4 + lk) ^ (row & 7)) * 16));
      }
#pragma unroll
      for (int mt = 0; mt < 2; ++mt)
#pragma unroll
        for (int nt = 0; nt < 4; ++nt)
          acc[mt][nt] = __builtin_amdgcn_mfma_f32_16x16x32_bf16(a[mt], b[nt], acc[mt][nt], 0, 0, 0);
    }
    __syncthreads();
    buf ^= 1;
  }
#pragma unroll
  for (int nt = 0; nt < 4; ++nt) {
    int col = n0 + nt * 16 + q;
    float bv = bias[col];
#pragma unroll
    for (int mt = 0; mt < 2; ++mt) {
      int rowb = m0 + wave * 32 + mt * 16 + lk * 4;
#pragma unroll
      for (int rr = 0; rr < 4; ++rr) {
        float v = acc[mt][nt][rr] + bv;
        size_t off = (size_t)(rowb + rr) * N + col;
        if (RESID) Cout[off] = f2bf(v + bf2f(res[off]));
        else       Cout[off] = f2bf(v * osc);
      }
    }
  }
}

// merged Q-proj + KV-proj. grid 1536 (XCD-swizzled): l<512 -> Q, else KV.
__global__ __launch_bounds__(256, 3)
void k_projmm(const unsigned short* __restrict__ Xb, const unsigned short* __restrict__ Cb,
              const unsigned short* __restrict__ Wqt, const unsigned short* __restrict__ Wkvt,
              const float* __restrict__ bq, const float* __restrict__ bkv,
              unsigned short* __restrict__ Qb, unsigned short* __restrict__ KVb) {
  __shared__ __align__(16) unsigned short Als[2 * 128 * 64];
  __shared__ __align__(16) unsigned short Bls[2 * 64 * 64];
  int bid = blockIdx.x;
  int l = (bid & 7) * 192 + (bid >> 3);
  const float c1 = 0.125f * 1.44269504088896340736f;
  if (l < 512) {
    int m = l >> 3, n = l & 7;
    gemm128x64<0>(Xb, Wqt, bq, nullptr, Qb, 512, 512, m * 128, n * 64, c1, Als, Bls);
  } else {
    int l2 = l - 512;
    int m = l2 >> 4, n = l2 & 15;
    gemm128x64<0>(Cb, Wkvt, bkv, nullptr, KVb, 1024, 512, m * 128, n * 64, 1.0f, Als, Bls);
  }
}

// O-proj + bias + bf16 residual -> bf16 tmp. grid 512 (XCD-swizzled).
__global__ __launch_bounds__(256, 3)
void k_omm(const unsigned short* __restrict__ Abuf, const unsigned short* __restrict__ Wot,
           const float* __restrict__ bo, const unsigned short* __restrict__ residb,
           unsigned short* __restrict__ tmp) {
  __shared__ __align__(16) unsigned short Als[2 * 128 * 64];
  __shared__ __align__(16) unsigned short Bls[2 * 64 * 64];
  int bid = blockIdx.x;
  int l = (bid & 7) * 64 + (bid >> 3);
  int m = l >> 3, n = l & 7;
  gemm128x64<1>(Abuf, Wot, bo, residb, tmp, 512, 512, m * 128, n * 64, 1.0f, Als, Bls);
}

// ---------------- flash attention v13 ---------------------------------------
// Round-13 algorithm (58.5 µs measured) with the tile loop fully statically
// unrolled: V in 4 buffers (cycle period 4), peel kb=0..3 and kb=28..31,
// 6 groups of 4 guard-free bodies between. All LDS pointers and staging
// targets are compile-time constants; no per-iter buffer selects.
// grid 1024 (XCD-swizzled): 32 (b,h) * 32 q-tiles(64); 4 waves * 16 q-rows.
// No-max softmax (Q pre-scaled by 0.125*log2e); P via permlane swaps;
// V token-permuted + ds_read_b64_tr_b16; PV lagged one tile.
__global__ __launch_bounds__(256, 3)
void k_attn(const unsigned short* __restrict__ Qb,
            const unsigned short* __restrict__ KVb,
            unsigned short* __restrict__ Ab) {
  __shared__ __align__(16) unsigned short Klds[2][64 * 64];
  __shared__ __align__(16) unsigned short Vlds[4][4096];
  int tid  = threadIdx.x;
  int lane = tid & 63, wave = tid >> 6;
  int q    = lane & 15, lk = lane >> 4;
  int bid = blockIdx.x;
  int swz = (bid & 7) * 128 + (bid >> 3);   // 128 blocks (4 bh) per XCD
  int qt = swz & 31, bh = swz >> 5;
  int b  = bh >> 3, h = bh & 7;
  int q0 = qt * 64 + wave * 16;
  const size_t kvbase = (size_t)b * SEQ * 1024;

  // Q fragments (16 rows per wave)
  bf16x8 qf0, qf1;
  {
    size_t qrow = (size_t)b * SEQ + q0 + q;
    qf0 = *(const bf16x8*)(Qb + qrow * DM + h * HD + lk * 8);
    qf1 = *(const bf16x8*)(Qb + qrow * DM + h * HD + 32 + lk * 8);
  }
  f32x4 acc[4];
#pragma unroll
  for (int i = 0; i < 4; ++i) acc[i] = f32x4{0.f,0.f,0.f,0.f};
  float l = 0.f;            // per-lane partial row-sum (reduced at the end)
  u32x4 pbA[2];

  // ---- strength-reduced staging pointers (advance += 65536 per tile) ----
  const unsigned short *gK0, *gK1, *gV0, *gV1;
  {
    int r0 = tid >> 3, s0_ = (tid & 7) ^ (r0 & 7);
    gK0 = KVb + kvbase + (size_t)r0 * 1024 + h * HD + s0_ * 8;
    int i1 = tid + 256, r1 = i1 >> 3, s1_ = (i1 & 7) ^ (r1 & 7);
    gK1 = KVb + kvbase + (size_t)r1 * 1024 + h * HD + s1_ * 8;
    int dt0 = tid >> 7, w0 = tid & 127, p0 = w0 >> 1, c80 = (w0 & 1) * 8;
    int t0 = (p0 & 32) + (((p0 >> 2) & 3) << 3) + (((p0 >> 4) & 1) << 2) + (p0 & 3);
    gV0 = KVb + kvbase + (size_t)t0 * 1024 + 512 + h * HD + dt0 * 16 + c80;
    int i1v = tid + 256, dt1 = i1v >> 7, w1 = i1v & 127, p1 = w1 >> 1, c81 = (w1 & 1) * 8;
    int t1 = (p1 & 32) + (((p1 >> 2) & 3) << 3) + (((p1 >> 4) & 1) << 2) + (p1 & 3);
    gV1 = KVb + kvbase + (size_t)t1 * 1024 + 512 + h * HD + dt1 * 16 + c81;
  }
  char* kw0 = (char*)Klds[0] + tid * 16;
  char* kw1 = (char*)Klds[1] + tid * 16;
  char* vw0 = (char*)Vlds[0] + tid * 16;
  char* vw1 = (char*)Vlds[1] + tid * 16;
  char* vw2 = (char*)Vlds[2] + tid * 16;
  char* vw3 = (char*)Vlds[3] + tid * 16;
  const char* kr0 = (const char*)Klds[0];
  const char* kr1 = (const char*)Klds[1];
  const char* vr0 = (const char*)Vlds[0] + lane * 8;
  const char* vr1 = (const char*)Vlds[1] + lane * 8;
  const char* vr2 = (const char*)Vlds[2] + lane * 8;
  const char* vr3 = (const char*)Vlds[3] + lane * 8;

#define STAGE(kd_, vd_) do {                        \
    load_lds16(gK0, (kd_));                         \
    load_lds16(gK1, (kd_) + 4096);                  \
    load_lds16(gV0, (vd_));                         \
    load_lds16(gV1, (vd_) + 4096);                  \
    gK0 += 65536; gK1 += 65536;                     \
    gV0 += 65536; gV1 += 65536;                     \
  } while (0)

// one tile body; DO_PV/DO_STAGE are literal 0/1; buffers are fixed pointers
#define ABODY(DO_PV, DO_STAGE, kdst_, vdst_, krd_, vprd_) do {               \
    if (DO_STAGE) STAGE(kdst_, vdst_);                                       \
    if (DO_PV) {                                                             \
      u32x2 tr[4][2][2];                                                     \
      _Pragma("unroll")                                                      \
      for (int dt = 0; dt < 4; ++dt)                                         \
        _Pragma("unroll")                                                    \
        for (int ks2 = 0; ks2 < 2; ++ks2)                                    \
          _Pragma("unroll")                                                  \
          for (int u = 0; u < 2; ++u)                                        \
            tr[dt][ks2][u] = ds_tr16((vprd_) + dt * 2048 + ks2 * 1024 + u * 512); \
      asm volatile("s_waitcnt lgkmcnt(0)" ::: "memory");                     \
      __builtin_amdgcn_sched_barrier(0);                                     \
      __builtin_amdgcn_s_setprio(1);                                         \
      _Pragma("unroll")                                                      \
      for (int ks2 = 0; ks2 < 2; ++ks2) {                                    \
        union { u32x4 u; bf16x8 v; } pb;                                     \
        pb.u = pbA[ks2];                                                     \
        _Pragma("unroll")                                                    \
        for (int dt = 0; dt < 4; ++dt) {                                     \
          union { u32x4 u; bf16x8 v; } cv;                                   \
          cv.u[0] = tr[dt][ks2][0][0]; cv.u[1] = tr[dt][ks2][0][1];          \
          cv.u[2] = tr[dt][ks2][1][0]; cv.u[3] = tr[dt][ks2][1][1];          \
          acc[dt] = __builtin_amdgcn_mfma_f32_16x16x32_bf16(cv.v, pb.v, acc[dt], 0, 0, 0); \
        }                                                                    \
      }                                                                      \
      __builtin_amdgcn_s_setprio(0);                                         \
    }                                                                        \
    f32x4 st[4];                                                             \
    _Pragma("unroll")                                                        \
    for (int kt = 0; kt < 4; ++kt) st[kt] = f32x4{0.f,0.f,0.f,0.f};          \
    __builtin_amdgcn_s_setprio(1);                                           \
    _Pragma("unroll")                                                        \
    for (int kt = 0; kt < 4; ++kt) {                                         \
      int row = kt * 16 + q;                                                 \
      bf16x8 kf0 = *(const bf16x8*)((krd_) + row * 128 + ((lk ^ (row & 7)) * 16)); \
      bf16x8 kf1 = *(const bf16x8*)((krd_) + row * 128 + (((4 + lk) ^ (row & 7)) * 16)); \
      st[kt] = __builtin_amdgcn_mfma_f32_16x16x32_bf16(kf0, qf0, st[kt], 0, 0, 0); \
      st[kt] = __builtin_amdgcn_mfma_f32_16x16x32_bf16(kf1, qf1, st[kt], 0, 0, 0); \
    }                                                                        \
    __builtin_amdgcn_s_setprio(0);                                           \
    float p[4][4];                                                           \
    _Pragma("unroll")                                                        \
    for (int kt = 0; kt < 4; ++kt)                                           \
      _Pragma("unroll")                                                      \
      for (int r = 0; r < 4; ++r) {                                          \
        float pe = __builtin_amdgcn_exp2f(st[kt][r]);                        \
        p[kt][r] = pe;                                                       \
        l += pe;                                                             \
      }                                                                      \
    _Pragma("unroll")                                                        \
    for (int ks2 = 0; ks2 < 2; ++ks2) {                                      \
      unsigned u0 = pack_bf2(p[2*ks2][0],     p[2*ks2][1]);                  \
      unsigned u1 = pack_bf2(p[2*ks2][2],     p[2*ks2][3]);                  \
      unsigned u2 = pack_bf2(p[2*ks2 + 1][0], p[2*ks2 + 1][1]);              \
      unsigned u3 = pack_bf2(p[2*ks2 + 1][2], p[2*ks2 + 1][3]);              \
      asm("v_permlane32_swap_b32 %0, %1" : "+v"(u0), "+v"(u2));              \
      asm("v_permlane32_swap_b32 %0, %1" : "+v"(u1), "+v"(u3));              \
      asm("v_permlane16_swap_b32 %0, %1" : "+v"(u0), "+v"(u2));              \
      asm("v_permlane16_swap_b32 %0, %1" : "+v"(u1), "+v"(u3));              \
      pbA[ks2][0] = u0; pbA[ks2][1] = u1;                                    \
      pbA[ks2][2] = u2; pbA[ks2][3] = u3;                                    \
    }                                                                        \
    __syncthreads();                                                         \
  } while (0)

  // prologue: tile 0 -> K[0], V[0]
  STAGE(kw0, vw0);
  __syncthreads();

  // kb=0..3 (peeled)
  ABODY(0, 1, kw1, vw1, kr0, vr0);
  ABODY(1, 1, kw0, vw2, kr1, vr0);
  ABODY(1, 1, kw1, vw3, kr0, vr1);
  ABODY(1, 1, kw0, vw0, kr1, vr2);
  // kb=4..27: 6 groups of 4
  for (int g = 0; g < 6; ++g) {
    ABODY(1, 1, kw1, vw1, kr0, vr3);
    ABODY(1, 1, kw0, vw2, kr1, vr0);
    ABODY(1, 1, kw1, vw3, kr0, vr1);
    ABODY(1, 1, kw0, vw0, kr1, vr2);
  }
  // kb=28..31 (peeled; kb=31 does not stage)
  ABODY(1, 1, kw1, vw1, kr0, vr3);
  ABODY(1, 1, kw0, vw2, kr1, vr0);
  ABODY(1, 1, kw1, vw3, kr0, vr1);
  ABODY(1, 0, kw0, vw0, kr1, vr2);

  // ---- final lagged PV(31): V[31&3] = V[3] ----
  {
    u32x2 tr[4][2][2];
#pragma unroll
    for (int dt = 0; dt < 4; ++dt)
#pragma unroll
      for (int ks2 = 0; ks2 < 2; ++ks2)
#pragma unroll
        for (int u = 0; u < 2; ++u)
          tr[dt][ks2][u] = ds_tr16(vr3 + dt * 2048 + ks2 * 1024 + u * 512);
    asm volatile("s_waitcnt lgkmcnt(0)" ::: "memory");
    __builtin_amdgcn_sched_barrier(0);
#pragma unroll
    for (int ks2 = 0; ks2 < 2; ++ks2) {
      union { u32x4 u; bf16x8 v; } pb;
      pb.u = pbA[ks2];
#pragma unroll
      for (int dt = 0; dt < 4; ++dt) {
        union { u32x4 u; bf16x8 v; } cv;
        cv.u[0] = tr[dt][ks2][0][0]; cv.u[1] = tr[dt][ks2][0][1];
        cv.u[2] = tr[dt][ks2][1][0]; cv.u[3] = tr[dt][ks2][1][1];
        acc[dt] = __builtin_amdgcn_mfma_f32_16x16x32_bf16(cv.v, pb.v, acc[dt], 0, 0, 0);
      }
    }
  }

  // ---- deferred row-sum + epilogue ----
  l += __shfl_xor(l, 16);
  l += __shfl_xor(l, 32);
  float inv = 1.0f / l;
  size_t orow = ((size_t)b * SEQ + q0 + q) * DM + h * HD + lk * 4;
#pragma unroll
  for (int dt = 0; dt < 4; ++dt) {
    u16x4 o;
#pragma unroll
    for (int r = 0; r < 4; ++r) o[r] = f2bf(acc[dt][r] * inv);
    *(u16x4*)(Ab + orow + dt * 16) = o;
  }
#undef STAGE
#undef ABODY
}

// ---------------- LayerNorm (wave per row, bf16 input) ----------------
__global__ void k_ln(const unsigned short* __restrict__ x, const float* __restrict__ gamma,
                     const float* __restrict__ beta, float* __restrict__ out) {
  int tid = threadIdx.x, lane = tid & 63, wave = tid >> 6;
  size_t row = (size_t)blockIdx.x * 4 + wave;
  u16x8 xv = *(const u16x8*)(x + row * DM + lane * 8);
  float v[8];
#pragma unroll
  for (int i = 0; i < 8; ++i) v[i] = bf2f(xv[i]);
  float s  = (v[0]+v[1]) + (v[2]+v[3]) + (v[4]+v[5]) + (v[6]+v[7]);
  float ss = (v[0]*v[0]+v[1]*v[1]) + (v[2]*v[2]+v[3]*v[3])
           + (v[4]*v[4]+v[5]*v[5]) + (v[6]*v[6]+v[7]*v[7]);
#pragma unroll
  for (int off = 1; off < 64; off <<= 1) {
    s  += __shfl_xor(s, off);
    ss += __shfl_xor(ss, off);
  }
  float mu  = s * (1.0f / DM);
  float var = ss * (1.0f / DM) - mu * mu;
  float w = rsqrtf(var + 1e-5f);
  fl4 g0 = *(const fl4*)(gamma + lane*8), g1 = *(const fl4*)(gamma + lane*8 + 4);
  fl4 b0 = *(const fl4*)(beta + lane*8),  b1 = *(const fl4*)(beta + lane*8 + 4);
  fl4 o0, o1;
#pragma unroll
  for (int i = 0; i < 4; ++i) {
    o0[i] = (v[i]     - mu) * w * g0[i] + b0[i];
    o1[i] = (v[4 + i] - mu) * w * g1[i] + b1[i];
  }
  float* orow = out + row * DM + lane * 8;
  *(fl4*)orow = o0;
  *(fl4*)(orow + 4) = o1;
}

extern "C" void kernel_launch(void* const* d_in, const int* in_sizes, int n_in,
                              void* d_out, int out_size, void* d_ws, size_t ws_size,
                              hipStream_t stream) {
  const float* layer_input = (const float*)d_in[0];
  const float* cross       = (const float*)d_in[1];
  const float* Wq   = (const float*)d_in[2];
  const float* bq   = (const float*)d_in[3];
  const float* Wkv  = (const float*)d_in[4];
  const float* bkv  = (const float*)d_in[5];
  const float* Wo   = (const float*)d_in[6];
  const float* bo   = (const float*)d_in[7];
  const float* gamma = (const float*)d_in[8];
  const float* beta  = (const float*)d_in[9];
  float* out = (float*)d_out;

  char* ws = (char*)d_ws;
  unsigned short* Xb   = (unsigned short*)(ws + (size_t)0);
  unsigned short* Cb   = (unsigned short*)(ws + ((size_t)8  << 20));
  unsigned short* Qb   = (unsigned short*)(ws + ((size_t)16 << 20));
  unsigned short* KVb  = (unsigned short*)(ws + ((size_t)24 << 20));
  unsigned short* Abuf = (unsigned short*)(ws + ((size_t)40 << 20));
  unsigned short* tmpb = (unsigned short*)(ws + ((size_t)48 << 20));
  unsigned short* Wqt  = (unsigned short*)(ws + ((size_t)64 << 20));
  unsigned short* Wkvt = (unsigned short*)(ws + ((size_t)65 << 20));
  unsigned short* Wot  = (unsigned short*)(ws + ((size_t)67 << 20));

  // preprocessing: both casts + all 3 weight transposes
  k_pre<<<8448, 256, 0, stream>>>(layer_input, Xb, cross, Cb,
                                  Wq, Wqt, Wkv, Wkvt, Wo, Wot);
  // merged Q + KV projections (Q pre-scaled by 0.125*log2e)
  k_projmm<<<1536, 256, 0, stream>>>(Xb, Cb, Wqt, Wkvt, bq, bkv, Qb, KVb);
  // attention (1024 blocks, XCD-swizzled inside; 3 blocks/CU)
  k_attn<<<1024, 256, 0, stream>>>(Qb, KVb, Abuf);
  // output projection + bias + bf16 residual -> bf16 tmp
  k_omm<<<512, 256, 0, stream>>>(Abuf, Wot, bo, Xb, tmpb);
  // layernorm (bf16 in, f32 out)
  k_ln<<<MTOT/4, 256, 0, stream>>>(tmpb, gamma, beta, out);
}